// Round 18
// baseline (127.610 us; speedup 1.0000x reference)
//
#include <hip/hip_runtime.h>
#include <cstdint>
#include <cstddef>

typedef _Float16 f16;
typedef f16 f16x2 __attribute__((ext_vector_type(2)));
typedef f16 f16x4 __attribute__((ext_vector_type(4)));
typedef f16 f16x8 __attribute__((ext_vector_type(8)));
typedef __fp16 hf16x2 __attribute__((ext_vector_type(2)));  // cvt_pkrtz return type
typedef float f32x4 __attribute__((ext_vector_type(4)));
typedef float f32x16 __attribute__((ext_vector_type(16)));
typedef unsigned int u32;

#define S_LEN 2048
#define DIM 1024
#define NBATCH 2
#define NHEAD 16
#define HDIM 64
#define M_TOT (NBATCH * S_LEN)  // 4096

// Q scale folds 1/sqrt(Hd) AND log2(e) so softmax uses exp2 directly.
#define QSCALE 0.18033688011112042f  // 0.125 * 1.4426950408889634

// ---- workspace layout (bytes) ----
#define OFF_XQ 0ull
#define OFF_XK (OFF_XQ + (size_t)M_TOT * DIM * 2)
#define OFF_XV (OFF_XK + (size_t)M_TOT * DIM * 2)
#define OFF_WT (OFF_XV + (size_t)M_TOT * DIM * 2)          // 4 mats, [N][K] f16
#define OFF_Q  (OFF_WT + 4ull * DIM * DIM * 2)             // fragment-native layouts
#define OFF_K  (OFF_Q + (size_t)M_TOT * DIM * 2)
#define OFF_VT (OFF_K + (size_t)M_TOT * DIM * 2)
#define OFF_AO (OFF_VT + (size_t)M_TOT * DIM * 2)

// ---------------- async global->LDS (width 16) ----------------
typedef const __attribute__((address_space(1))) void GVp;
typedef __attribute__((address_space(3))) void LVp;
__device__ __forceinline__ void gload16(const void* g, void* l) {
  __builtin_amdgcn_global_load_lds((GVp*)g, (LVp*)l, 16, 0, 0);
}

__device__ __forceinline__ float fast_exp2(float x) {
  float r;
  asm("v_exp_f32 %0, %1" : "=v"(r) : "v"(x));
  return r;
}

// publish LDS writes; NO vmcnt drain (reg loads are wave-private and fly across)
#define SYNCL()                                              \
  do {                                                       \
    asm volatile("s_waitcnt lgkmcnt(0)" ::: "memory");       \
    __builtin_amdgcn_sched_barrier(0);                       \
    __builtin_amdgcn_s_barrier();                            \
    __builtin_amdgcn_sched_barrier(0);                       \
  } while (0)

// ------- merged prep: cast X (y=0..2) + transpose W (y=3, x<1024) -------
__global__ __launch_bounds__(256) void prep_kernel(
    const float* __restrict__ q, const float* __restrict__ k, const float* __restrict__ v,
    const float* __restrict__ Wq, const float* __restrict__ Wk,
    const float* __restrict__ Wv, const float* __restrict__ Wp,
    f16* __restrict__ oq, f16* __restrict__ ok, f16* __restrict__ ov,
    f16* __restrict__ wt_out) {
  __shared__ f16 tile[64][72];
  if (blockIdx.y < 3) {
    const float* src = blockIdx.y == 0 ? q : blockIdx.y == 1 ? k : v;
    f16* dst = blockIdx.y == 0 ? oq : blockIdx.y == 1 ? ok : ov;
    size_t i = ((size_t)blockIdx.x * 256 + threadIdx.x) * 8;
    float4 a = *(const float4*)(src + i);
    float4 b = *(const float4*)(src + i + 4);
    f16x8 o;
    o[0] = (f16)a.x; o[1] = (f16)a.y; o[2] = (f16)a.z; o[3] = (f16)a.w;
    o[4] = (f16)b.x; o[5] = (f16)b.y; o[6] = (f16)b.z; o[7] = (f16)b.w;
    *(f16x8*)(dst + i) = o;
    return;
  }
  if (blockIdx.x >= 1024) return;                  // uniform per block: safe
  const int bz = blockIdx.x >> 8;                  // 0..3 -> Wq/Wk/Wv/Wp
  const int bx = blockIdx.x & 15, by = (blockIdx.x >> 4) & 15;
  const float* W = bz == 0 ? Wq : bz == 1 ? Wk : bz == 2 ? Wv : Wp;
  f16* Wt = wt_out + (size_t)bz * DIM * DIM;
  const int kt = bx * 64, nt = by * 64;
  const int t = threadIdx.x, r = t >> 2, c0 = (t & 3) * 16;
#pragma unroll
  for (int i = 0; i < 16; i += 4) {
    float4 vv = *(const float4*)(W + (size_t)(kt + r) * DIM + nt + c0 + i);
    tile[r][c0 + i + 0] = (f16)vv.x; tile[r][c0 + i + 1] = (f16)vv.y;
    tile[r][c0 + i + 2] = (f16)vv.z; tile[r][c0 + i + 3] = (f16)vv.w;
  }
  __syncthreads();
  f16x8 o0, o1;
#pragma unroll
  for (int i = 0; i < 8; ++i) { o0[i] = tile[c0 + i][r]; o1[i] = tile[c0 + 8 + i][r]; }
  *(f16x8*)(Wt + (size_t)(nt + r) * DIM + kt + c0) = o0;
  *(f16x8*)(Wt + (size_t)(nt + r) * DIM + kt + c0 + 8) = o1;
}

// ------- 128x128 f16 GEMM core, T2-swizzled LDS (r13-validated) -------
__device__ __forceinline__ void gemm_core_sw(const f16* __restrict__ A, const f16* __restrict__ B,
                                             char* lds, f32x4 acc[4][4]) {
  const int tid = threadIdx.x;
  const int wid = tid >> 6, lane = tid & 63;
  const int l15 = lane & 15, l4 = lane >> 4;
  const int wm = (wid >> 1) * 64, wn = (wid & 1) * 64;
  const int rr = tid >> 2, cc = tid & 3;
  const int ccs = cc ^ ((rr >> 1) & 3);                    // pre-swizzled source slot
  const f16* gA = A + (size_t)rr * DIM + ccs * 8;
  const f16* gB = B + (size_t)rr * DIM + ccs * 8;
  const int ldst = wid * 1024;

  gload16(gA,            lds + ldst);
  gload16(gA + 64 * DIM, lds + 4096 + ldst);
  gload16(gB,            lds + 8192 + ldst);
  gload16(gB + 64 * DIM, lds + 12288 + ldst);
  __syncthreads();

  const int sw = (l15 >> 1) & 3;
  for (int kt = 0; kt < DIM / 32; ++kt) {
    char* cur = lds + (kt & 1) * 16384;
    if (kt + 1 < DIM / 32) {
      char* nxt = lds + ((kt + 1) & 1) * 16384;
      const f16* ga = gA + (kt + 1) * 32;
      const f16* gb = gB + (kt + 1) * 32;
      gload16(ga,            nxt + ldst);
      gload16(ga + 64 * DIM, nxt + 4096 + ldst);
      gload16(gb,            nxt + 8192 + ldst);
      gload16(gb + 64 * DIM, nxt + 12288 + ldst);
    }
    f16x8 af[4], bf[4];
#pragma unroll
    for (int mt = 0; mt < 4; ++mt)
      af[mt] = *(const f16x8*)(cur + (wm + mt * 16 + l15) * 64 + (l4 ^ sw) * 16);
#pragma unroll
    for (int nt = 0; nt < 4; ++nt)
      bf[nt] = *(const f16x8*)(cur + 8192 + (wn + nt * 16 + l15) * 64 + (l4 ^ sw) * 16);
#pragma unroll
    for (int mt = 0; mt < 4; ++mt)
#pragma unroll
      for (int nt = 0; nt < 4; ++nt)
        acc[mt][nt] = __builtin_amdgcn_mfma_f32_16x16x32_f16(af[mt], bf[nt], acc[mt][nt], 0, 0, 0);
    __syncthreads();
  }
}

// Fragment-native addresses (elements) within one (batch,head) panel:
//  Q/K: A(s,d) = (s>>5)*2048 + (d>>4)*512 + ((d>>3)&1)*256 + (s&31)*8 + (d&7)
//       -> contiguous 512B blocks indexed (s>>5, d>>4, (d>>3)&1)
//  V:   A(s,d) = (s>>6)*4096 + (d>>5)*2048 + ((s>>4)&3)*512 + ((s>>3)&1)*256 + (d&31)*8 + (s&7)
//       -> contiguous 512B blocks indexed (s>>3, d>>5)

// ---------------- batched QKV projection (f16 inputs) ----------------
// Epilogue: stage output tile in LDS (panel layout), then 512B coalesced stores.
__global__ __launch_bounds__(256) void proj_kernel(
    const f16* __restrict__ Xq, const f16* __restrict__ Xk, const f16* __restrict__ Xv,
    const f16* __restrict__ Wt,
    const float* __restrict__ bq, const float* __restrict__ bk, const float* __restrict__ bv,
    f16* __restrict__ Q, f16* __restrict__ Kh, f16* __restrict__ Vt) {
  __shared__ __align__(16) char lds[32768];
  const int m0 = blockIdx.x * 128, n0 = blockIdx.y * 128;
  const int z = blockIdx.z;
  const f16* X = z == 0 ? Xq : z == 1 ? Xk : Xv;
  const f16* W = Wt + (size_t)z * DIM * DIM;
  const float* bias = z == 0 ? bq : z == 1 ? bk : bv;
  f32x4 acc[4][4] = {};
  gemm_core_sw(X + (size_t)m0 * DIM, W + (size_t)n0 * DIM, lds, acc);

  const int tid = threadIdx.x, wid = tid >> 6, lane = tid & 63;
  const int l15 = lane & 15, l4 = lane >> 4;
  const int wm = (wid >> 1) * 64;                    // wn = (wid&1)*64 -> hloc = wid&1
  const int hloc1 = wid & 1;
  f16* lt = (f16*)lds;                               // 16384 f16 = 32KB, free after loop

  // ---- phase 1: scatter acc -> LDS in panel layout (per head-half 8192 elems) ----
  if (z != 2) {
#pragma unroll
    for (int nt = 0; nt < 4; ++nt) {
      const int col = n0 + hloc1 * 64 + nt * 16 + l15;
      const float bb = bias[col];
#pragma unroll
      for (int mt = 0; mt < 4; ++mt)
#pragma unroll
        for (int j = 0; j < 4; ++j) {
          float v = acc[mt][nt][j] + bb;
          if (z == 0) v *= QSCALE;
          const int off = hloc1 * 8192 + ((wm >> 5) + (mt >> 1)) * 2048 + nt * 512 +
                          (l15 >> 3) * 256 + ((mt & 1) * 16 + l4 * 4 + j) * 8 + (l15 & 7);
          lt[off] = (f16)v;
        }
    }
  } else {
#pragma unroll
    for (int nt = 0; nt < 4; ++nt) {
      const int col = n0 + hloc1 * 64 + nt * 16 + l15;
      const float bb = bias[col];
#pragma unroll
      for (int mt = 0; mt < 4; ++mt)
#pragma unroll
        for (int j = 0; j < 4; ++j) {
          const float v = acc[mt][nt][j] + bb;
          const int off = hloc1 * 8192 + ((wm >> 3) + mt * 2 + (l4 >> 1)) * 512 +
                          (nt >> 1) * 256 + ((nt & 1) * 16 + l15) * 8 + (l4 & 1) * 4 + j;
          lt[off] = (f16)v;
        }
    }
  }
  __syncthreads();

  // ---- phase 2: 16 x 512B coalesced block stores per wave (8B/lane) ----
  const int nb = m0 >> 11;                           // batch (tile never crosses boundary)
  const int hh = (n0 >> 6) + (wid >> 1);             // waves 0,1 -> head0; 2,3 -> head1
  const int w16 = wid * 16;
  const int sbase = m0 & (S_LEN - 1);
  f16* outp = (z == 0 ? Q : z == 1 ? Kh : Vt) + (size_t)(nb * NHEAD + hh) * (S_LEN * HDIM);
  if (z != 2) {
    const int sb5 = sbase >> 5;
#pragma unroll
    for (int i = 0; i < 16; ++i) {
      const int blk = (w16 + i) & 31;
      const int st = blk >> 3, dt4 = (blk >> 1) & 3, dt8 = blk & 1;
      f16x4 vdat = *(const f16x4*)(lt + (w16 + i) * 256 + lane * 4);
      *(f16x4*)(outp + (sb5 + st) * 2048 + dt4 * 512 + dt8 * 256 + lane * 4) = vdat;
    }
  } else {
#pragma unroll
    for (int i = 0; i < 16; ++i) {
      const int blk = (w16 + i) & 31;
      const int s3 = blk >> 1, D5 = blk & 1;
      const int sg = sbase + s3 * 8;
      f16x4 vdat = *(const f16x4*)(lt + (w16 + i) * 256 + lane * 4);
      *(f16x4*)(outp + (sg >> 6) * 4096 + D5 * 2048 + ((sg >> 4) & 3) * 512 +
                ((sg >> 3) & 1) * 256 + lane * 4) = vdat;
    }
  }
}

// ------- 64x128 f16 GEMM core (outproj) -------
__device__ __forceinline__ void gemm_core_sw64(const f16* __restrict__ A, const f16* __restrict__ B,
                                               char* lds, f32x4 acc[2][4]) {
  const int tid = threadIdx.x;
  const int wid = tid >> 6, lane = tid & 63;
  const int l15 = lane & 15, l4 = lane >> 4;
  const int wm = (wid >> 1) * 32, wn = (wid & 1) * 64;
  const int rr = tid >> 2, cc = tid & 3;
  const int ccs = cc ^ ((rr >> 1) & 3);                    // pre-swizzled source slot
  const f16* gA = A + (size_t)rr * DIM + ccs * 8;          // rows 0..63
  const f16* gB = B + (size_t)rr * DIM + ccs * 8;
  const int ldst = wid * 1024;

  gload16(gA,            lds + ldst);                      // A rows 0..63
  gload16(gB,            lds + 4096 + ldst);               // B rows 0..63
  gload16(gB + 64 * DIM, lds + 8192 + ldst);               // B rows 64..127
  __syncthreads();

  const int sw = (l15 >> 1) & 3;
  for (int kt = 0; kt < DIM / 32; ++kt) {
    char* cur = lds + (kt & 1) * 12288;
    if (kt + 1 < DIM / 32) {
      char* nxt = lds + ((kt + 1) & 1) * 12288;
      const f16* ga = gA + (kt + 1) * 32;
      const f16* gb = gB + (kt + 1) * 32;
      gload16(ga,            nxt + ldst);
      gload16(gb,            nxt + 4096 + ldst);
      gload16(gb + 64 * DIM, nxt + 8192 + ldst);
    }
    f16x8 af[2], bf[4];
#pragma unroll
    for (int mt = 0; mt < 2; ++mt)
      af[mt] = *(const f16x8*)(cur + (wm + mt * 16 + l15) * 64 + (l4 ^ sw) * 16);
#pragma unroll
    for (int nt = 0; nt < 4; ++nt)
      bf[nt] = *(const f16x8*)(cur + 4096 + (wn + nt * 16 + l15) * 64 + (l4 ^ sw) * 16);
#pragma unroll
    for (int mt = 0; mt < 2; ++mt)
#pragma unroll
      for (int nt = 0; nt < 4; ++nt)
        acc[mt][nt] = __builtin_amdgcn_mfma_f32_16x16x32_f16(af[mt], bf[nt], acc[mt][nt], 0, 0, 0);
    __syncthreads();
  }
}

// ---------------- output projection -> fp32 d_out (64-row tile, XCD-chunked) --------
__global__ __launch_bounds__(256) void outproj_kernel(
    const f16* __restrict__ A, const f16* __restrict__ Wt,
    const float* __restrict__ bias, float* __restrict__ Out) {
  __shared__ __align__(16) char lds[24576];
  const int fid = (int)blockIdx.x;                 // 0..511 linear
  const int c = fid >> 6, i = fid & 63;            // chunk (XCD), index-in-chunk
  const int mt_ = (i & 15) + (c >> 1) * 16;        // 0..63
  const int nt_ = ((i >> 4) & 3) + (c & 1) * 4;    // 0..7
  const int m0 = mt_ * 64, n0 = nt_ * 128;
  f32x4 acc[2][4] = {};
  gemm_core_sw64(A + (size_t)m0 * DIM, Wt + (size_t)n0 * DIM, lds, acc);

  const int tid = threadIdx.x, wid = tid >> 6, lane = tid & 63;
  const int l15 = lane & 15, l4 = lane >> 4;
  const int wm = (wid >> 1) * 32, wn = (wid & 1) * 64;
#pragma unroll
  for (int nt = 0; nt < 4; ++nt) {
    const int col = n0 + wn + nt * 16 + l15;
    const float bb = bias[col];
#pragma unroll
    for (int mt = 0; mt < 2; ++mt)
#pragma unroll
      for (int j = 0; j < 4; ++j) {
        const int row = m0 + wm + mt * 16 + l4 * 4 + j;
        Out[(size_t)row * DIM + col] = acc[mt][nt][j] + bb;
      }
  }
}

// -------- flash attention (frozen best): reg-staged async-split (T14) + XCD swizzle (T1) ----
__global__ __launch_bounds__(256, 2) void attn_kernel(
    const f16* __restrict__ Q, const f16* __restrict__ K,
    const f16* __restrict__ Vt, f16* __restrict__ AO) {
  const int bid = blockIdx.x;
  const int sbid = (bid & 7) * 64 + (bid >> 3);    // bijective: 512 % 8 == 0
  const int qt = sbid & 15, h = (sbid >> 4) & 15, b = sbid >> 8;
  const int tid = threadIdx.x;
  const int lane = tid & 63, wid = tid >> 6;
  const int l31 = lane & 31, hi = lane >> 5;

  __shared__ __align__(16) char kv_lds[2][16384];  // [buf][K 8KB | V 8KB]

  const int q0 = qt * 128 + wid * 32;
  const size_t panel = (size_t)(b * NHEAD + h) * (S_LEN * HDIM);
  const f16* Qp = Q + panel + (size_t)(q0 >> 5) * 2048;
  const char* KpB = (const char*)(K + panel);
  const char* VpB = (const char*)(Vt + panel);

  f16x8 qf[4];
#pragma unroll
  for (int sk = 0; sk < 4; ++sk)
    qf[sk] = *(const f16x8*)(Qp + sk * 512 + hi * 256 + l31 * 8);

  f32x16 accO[2] = {};            // O^T[d][q]: dt in {0,1}, col=q=l31
  float lacc0 = 0.f, lacc1 = 0.f, lacc2 = 0.f, lacc3 = 0.f;

  auto LOADR = [&](int it, f32x4 (&R)[4]) {
    const char* gK = KpB + (size_t)it * 8192 + tid * 16;
    const char* gV = VpB + (size_t)it * 8192 + tid * 16;
    R[0] = *(const f32x4*)(gK);
    R[1] = *(const f32x4*)(gK + 4096);
    R[2] = *(const f32x4*)(gV);
    R[3] = *(const f32x4*)(gV + 4096);
  };
  auto WRITER = [&](const f32x4 (&R)[4], int buf) {
    char* p = &kv_lds[buf][(tid >> 6) * 1024 + (tid & 63) * 16];
    *(f32x4*)(p)         = R[0];
    *(f32x4*)(p + 4096)  = R[1];
    *(f32x4*)(p + 8192)  = R[2];
    *(f32x4*)(p + 12288) = R[3];
  };

  auto QK = [&](int buf, f32x16 (&st)[2]) {
    const char* lk = &kv_lds[buf][0];
    f16x8 kf[2][4];
#pragma unroll
    for (int tt = 0; tt < 2; ++tt)
#pragma unroll
      for (int sk = 0; sk < 4; ++sk)
        kf[tt][sk] = *(const f16x8*)(lk + tt * 4096 + sk * 1024 + lane * 16);
    __builtin_amdgcn_s_setprio(1);
#pragma unroll
    for (int tt = 0; tt < 2; ++tt) {
      st[tt] = (f32x16)(0.f);
#pragma unroll
      for (int sk = 0; sk < 4; ++sk)
        st[tt] = __builtin_amdgcn_mfma_f32_32x32x16_f16(kf[tt][sk], qf[sk], st[tt], 0, 0, 0);
    }
    __builtin_amdgcn_s_setprio(0);
  };

  auto PHASE = [&](f32x16 (&st)[2], int buf) {
    const char* lv = &kv_lds[buf][8192];
    f16x8 vf[2][4];
#pragma unroll
    for (int dt = 0; dt < 2; ++dt)
#pragma unroll
      for (int s = 0; s < 4; ++s)
        vf[dt][s] = *(const f16x8*)(lv + dt * 4096 + s * 1024 + lane * 16);

    u32 pk[2][8];
#pragma unroll
    for (int tt = 0; tt < 2; ++tt)
#pragma unroll
      for (int j = 0; j < 8; ++j) {
        const float p0 = fast_exp2(st[tt][2 * j]);
        const float p1 = fast_exp2(st[tt][2 * j + 1]);
        const float ps = p0 + p1;
        if (((tt * 8 + j) & 3) == 0) lacc0 += ps;
        else if (((tt * 8 + j) & 3) == 1) lacc1 += ps;
        else if (((tt * 8 + j) & 3) == 2) lacc2 += ps;
        else lacc3 += ps;
        union { hf16x2 h; u32 w; } cv;
        cv.h = __builtin_amdgcn_cvt_pkrtz(p0, p1);
        pk[tt][j] = cv.w;
      }

    __builtin_amdgcn_s_setprio(1);
#pragma unroll
    for (int s = 0; s < 4; ++s) {
      const int tt = s >> 1, sl = s & 1;
      u32 w0 = pk[tt][4 * sl + 0], w2 = pk[tt][4 * sl + 2];
      u32 w1 = pk[tt][4 * sl + 1], w3 = pk[tt][4 * sl + 3];
      asm("v_permlane32_swap_b32 %0, %1" : "+v"(w0), "+v"(w2));
      asm("v_permlane32_swap_b32 %0, %1" : "+v"(w1), "+v"(w3));
      union { u32 w[4]; f16x8 v; } pf;
      pf.w[0] = w0; pf.w[1] = w1; pf.w[2] = w2; pf.w[3] = w3;
      accO[0] = __builtin_amdgcn_mfma_f32_32x32x16_f16(vf[0][s], pf.v, accO[0], 0, 0, 0);
      accO[1] = __builtin_amdgcn_mfma_f32_32x32x16_f16(vf[1][s], pf.v, accO[1], 0, 0, 0);
    }
    __builtin_amdgcn_s_setprio(0);
  };

  const int NIT = S_LEN / 64;  // 32 (even)

  f32x4 RA[4], RB[4];
  f32x16 st[2];
  LOADR(0, RA);
  WRITER(RA, 0);               // compiler waits RA's vmcnt here (prologue only)
  LOADR(1, RB);                // in flight across the first barrier
  SYNCL();

  for (int it = 0; it < NIT; it += 2) {
    if (it + 2 < NIT) LOADR(it + 2, RA);
    QK(0, st);
    PHASE(st, 0);
    WRITER(RB, 1);             // vmcnt wait auto-inserted for RB only
    SYNCL();
    if (it + 3 < NIT) LOADR(it + 3, RB);
    QK(1, st);
    PHASE(st, 1);
    if (it + 2 < NIT) WRITER(RA, 0);
    SYNCL();
  }

  const float l_loc = (lacc0 + lacc1) + (lacc2 + lacc3);
  const float l_all = l_loc + __shfl_xor(l_loc, 32);
  const float inv = 1.f / l_all;
  f16* aop = AO + ((size_t)(b * S_LEN + q0 + l31)) * DIM + h * HDIM;
#pragma unroll
  for (int dt = 0; dt < 2; ++dt)
#pragma unroll
    for (int j = 0; j < 8; ++j) {
      union { f16x2 h; u32 w; } cv;
      cv.h[0] = (f16)(accO[dt][2 * j] * inv);
      cv.h[1] = (f16)(accO[dt][2 * j + 1] * inv);
      const int d = ((2 * j) & 3) + 8 * ((2 * j) >> 2) + 4 * hi + dt * 32;
      *(f16x2*)(aop + d) = cv.h;
    }
}

extern "C" void kernel_launch(void* const* d_in, const int* in_sizes, int n_in,
                              void* d_out, int out_size, void* d_ws, size_t ws_size,
                              hipStream_t stream) {
  (void)in_sizes; (void)n_in; (void)out_size; (void)ws_size;
  const float* q  = (const float*)d_in[0];
  const float* k  = (const float*)d_in[1];
  const float* v  = (const float*)d_in[2];
  const float* Wq = (const float*)d_in[3];
  const float* bq = (const float*)d_in[4];
  const float* Wk = (const float*)d_in[5];
  const float* bk = (const float*)d_in[6];
  const float* Wv = (const float*)d_in[7];
  const float* bv = (const float*)d_in[8];
  const float* Wp = (const float*)d_in[9];
  const float* bp = (const float*)d_in[10];

  char* ws = (char*)d_ws;
  f16* Xq  = (f16*)(ws + OFF_XQ);
  f16* Xk  = (f16*)(ws + OFF_XK);
  f16* Xv  = (f16*)(ws + OFF_XV);
  f16* Wt  = (f16*)(ws + OFF_WT);
  f16* Qs  = (f16*)(ws + OFF_Q);
  f16* Kh  = (f16*)(ws + OFF_K);
  f16* Vts = (f16*)(ws + OFF_VT);
  f16* AO  = (f16*)(ws + OFF_AO);

  prep_kernel<<<dim3(2048, 4, 1), 256, 0, stream>>>(q, k, v, Wq, Wk, Wv, Wp, Xq, Xk, Xv, Wt);
  proj_kernel<<<dim3(32, 8, 3), 256, 0, stream>>>(Xq, Xk, Xv, Wt, bq, bk, bv, Qs, Kh, Vts);
  attn_kernel<<<dim3(512, 1, 1), 256, 0, stream>>>(Qs, Kh, Vts, AO);
  outproj_kernel<<<dim3(512, 1, 1), 256, 0, stream>>>(AO, Wt + 3ull * DIM * DIM, bp, (float*)d_out);
}

// Round 19
// 126.446 us; speedup vs baseline: 1.0092x; 1.0092x over previous
//
#include <hip/hip_runtime.h>
#include <cstdint>
#include <cstddef>

typedef _Float16 f16;
typedef f16 f16x2 __attribute__((ext_vector_type(2)));
typedef f16 f16x8 __attribute__((ext_vector_type(8)));
typedef __fp16 hf16x2 __attribute__((ext_vector_type(2)));  // cvt_pkrtz return type
typedef float f32x4 __attribute__((ext_vector_type(4)));
typedef float f32x16 __attribute__((ext_vector_type(16)));
typedef unsigned int u32;

#define S_LEN 2048
#define DIM 1024
#define NBATCH 2
#define NHEAD 16
#define HDIM 64
#define M_TOT (NBATCH * S_LEN)  // 4096

// Q scale folds 1/sqrt(Hd) AND log2(e) so softmax uses exp2 directly.
#define QSCALE 0.18033688011112042f  // 0.125 * 1.4426950408889634

// ---- workspace layout (bytes) ----
#define OFF_XQ 0ull
#define OFF_XK (OFF_XQ + (size_t)M_TOT * DIM * 2)
#define OFF_XV (OFF_XK + (size_t)M_TOT * DIM * 2)
#define OFF_WT (OFF_XV + (size_t)M_TOT * DIM * 2)          // 4 mats, [N][K] f16
#define OFF_Q  (OFF_WT + 4ull * DIM * DIM * 2)             // fragment-native layouts
#define OFF_K  (OFF_Q + (size_t)M_TOT * DIM * 2)
#define OFF_VT (OFF_K + (size_t)M_TOT * DIM * 2)
#define OFF_AO (OFF_VT + (size_t)M_TOT * DIM * 2)

// ---------------- async global->LDS (width 16) ----------------
typedef const __attribute__((address_space(1))) void GVp;
typedef __attribute__((address_space(3))) void LVp;
__device__ __forceinline__ void gload16(const void* g, void* l) {
  __builtin_amdgcn_global_load_lds((GVp*)g, (LVp*)l, 16, 0, 0);
}

__device__ __forceinline__ float fast_exp2(float x) {
  float r;
  asm("v_exp_f32 %0, %1" : "=v"(r) : "v"(x));
  return r;
}

// publish LDS writes; NO vmcnt drain (reg loads are wave-private and fly across)
#define SYNCL()                                              \
  do {                                                       \
    asm volatile("s_waitcnt lgkmcnt(0)" ::: "memory");       \
    __builtin_amdgcn_sched_barrier(0);                       \
    __builtin_amdgcn_s_barrier();                            \
    __builtin_amdgcn_sched_barrier(0);                       \
  } while (0)

// ------- merged prep: cast X (y=0..2) + transpose W (y=3, x<1024) -------
__global__ __launch_bounds__(256) void prep_kernel(
    const float* __restrict__ q, const float* __restrict__ k, const float* __restrict__ v,
    const float* __restrict__ Wq, const float* __restrict__ Wk,
    const float* __restrict__ Wv, const float* __restrict__ Wp,
    f16* __restrict__ oq, f16* __restrict__ ok, f16* __restrict__ ov,
    f16* __restrict__ wt_out) {
  __shared__ f16 tile[64][72];
  if (blockIdx.y < 3) {
    const float* src = blockIdx.y == 0 ? q : blockIdx.y == 1 ? k : v;
    f16* dst = blockIdx.y == 0 ? oq : blockIdx.y == 1 ? ok : ov;
    size_t i = ((size_t)blockIdx.x * 256 + threadIdx.x) * 8;
    float4 a = *(const float4*)(src + i);
    float4 b = *(const float4*)(src + i + 4);
    f16x8 o;
    o[0] = (f16)a.x; o[1] = (f16)a.y; o[2] = (f16)a.z; o[3] = (f16)a.w;
    o[4] = (f16)b.x; o[5] = (f16)b.y; o[6] = (f16)b.z; o[7] = (f16)b.w;
    *(f16x8*)(dst + i) = o;
    return;
  }
  if (blockIdx.x >= 1024) return;                  // uniform per block: safe
  const int bz = blockIdx.x >> 8;                  // 0..3 -> Wq/Wk/Wv/Wp
  const int bx = blockIdx.x & 15, by = (blockIdx.x >> 4) & 15;
  const float* W = bz == 0 ? Wq : bz == 1 ? Wk : bz == 2 ? Wv : Wp;
  f16* Wt = wt_out + (size_t)bz * DIM * DIM;
  const int kt = bx * 64, nt = by * 64;
  const int t = threadIdx.x, r = t >> 2, c0 = (t & 3) * 16;
#pragma unroll
  for (int i = 0; i < 16; i += 4) {
    float4 vv = *(const float4*)(W + (size_t)(kt + r) * DIM + nt + c0 + i);
    tile[r][c0 + i + 0] = (f16)vv.x; tile[r][c0 + i + 1] = (f16)vv.y;
    tile[r][c0 + i + 2] = (f16)vv.z; tile[r][c0 + i + 3] = (f16)vv.w;
  }
  __syncthreads();
  f16x8 o0, o1;
#pragma unroll
  for (int i = 0; i < 8; ++i) { o0[i] = tile[c0 + i][r]; o1[i] = tile[c0 + 8 + i][r]; }
  *(f16x8*)(Wt + (size_t)(nt + r) * DIM + kt + c0) = o0;
  *(f16x8*)(Wt + (size_t)(nt + r) * DIM + kt + c0 + 8) = o1;
}

// ------- 128x128 f16 GEMM core, T2-swizzled LDS (r13-validated) -------
__device__ __forceinline__ void gemm_core_sw(const f16* __restrict__ A, const f16* __restrict__ B,
                                             char* lds, f32x4 acc[4][4]) {
  const int tid = threadIdx.x;
  const int wid = tid >> 6, lane = tid & 63;
  const int l15 = lane & 15, l4 = lane >> 4;
  const int wm = (wid >> 1) * 64, wn = (wid & 1) * 64;
  const int rr = tid >> 2, cc = tid & 3;
  const int ccs = cc ^ ((rr >> 1) & 3);                    // pre-swizzled source slot
  const f16* gA = A + (size_t)rr * DIM + ccs * 8;
  const f16* gB = B + (size_t)rr * DIM + ccs * 8;
  const int ldst = wid * 1024;

  gload16(gA,            lds + ldst);
  gload16(gA + 64 * DIM, lds + 4096 + ldst);
  gload16(gB,            lds + 8192 + ldst);
  gload16(gB + 64 * DIM, lds + 12288 + ldst);
  __syncthreads();

  const int sw = (l15 >> 1) & 3;
  for (int kt = 0; kt < DIM / 32; ++kt) {
    char* cur = lds + (kt & 1) * 16384;
    if (kt + 1 < DIM / 32) {
      char* nxt = lds + ((kt + 1) & 1) * 16384;
      const f16* ga = gA + (kt + 1) * 32;
      const f16* gb = gB + (kt + 1) * 32;
      gload16(ga,            nxt + ldst);
      gload16(ga + 64 * DIM, nxt + 4096 + ldst);
      gload16(gb,            nxt + 8192 + ldst);
      gload16(gb + 64 * DIM, nxt + 12288 + ldst);
    }
    f16x8 af[4], bf[4];
#pragma unroll
    for (int mt = 0; mt < 4; ++mt)
      af[mt] = *(const f16x8*)(cur + (wm + mt * 16 + l15) * 64 + (l4 ^ sw) * 16);
#pragma unroll
    for (int nt = 0; nt < 4; ++nt)
      bf[nt] = *(const f16x8*)(cur + 8192 + (wn + nt * 16 + l15) * 64 + (l4 ^ sw) * 16);
#pragma unroll
    for (int mt = 0; mt < 4; ++mt)
#pragma unroll
      for (int nt = 0; nt < 4; ++nt)
        acc[mt][nt] = __builtin_amdgcn_mfma_f32_16x16x32_f16(af[mt], bf[nt], acc[mt][nt], 0, 0, 0);
    __syncthreads();
  }
}

// Fragment-native addresses (elements) within one (batch,head) panel:
//  Q/K: tile32 = s>>5 ; addr = tile32*2048 + (d>>4)*512 + ((d>>3)&1)*256 + (s&31)*8 + (d&7)
//  V:   tile64 = s>>6 ; addr = tile64*4096 + (d>>5)*2048 + ((s>>4)&3)*512 + ((s>>3)&1)*256 + (d&31)*8 + (s&7)

// ---------------- batched QKV projection (f16 inputs) ----------------
__global__ __launch_bounds__(256) void proj_kernel(
    const f16* __restrict__ Xq, const f16* __restrict__ Xk, const f16* __restrict__ Xv,
    const f16* __restrict__ Wt,
    const float* __restrict__ bq, const float* __restrict__ bk, const float* __restrict__ bv,
    f16* __restrict__ Q, f16* __restrict__ Kh, f16* __restrict__ Vt) {
  __shared__ __align__(16) char lds[32768];
  const int m0 = blockIdx.x * 128, n0 = blockIdx.y * 128;
  const int z = blockIdx.z;
  const f16* X = z == 0 ? Xq : z == 1 ? Xk : Xv;
  const f16* W = Wt + (size_t)z * DIM * DIM;
  const float* bias = z == 0 ? bq : z == 1 ? bk : bv;
  f32x4 acc[4][4] = {};
  gemm_core_sw(X + (size_t)m0 * DIM, W + (size_t)n0 * DIM, lds, acc);

  const int tid = threadIdx.x, wid = tid >> 6, lane = tid & 63;
  const int l15 = lane & 15, l4 = lane >> 4;
  const int wm = (wid >> 1) * 64, wn = (wid & 1) * 64;
#pragma unroll
  for (int nt = 0; nt < 4; ++nt) {
    const int col = n0 + wn + nt * 16 + l15;
    const float bb = bias[col];
    const int hh = col >> 6, d = col & 63;
#pragma unroll
    for (int mt = 0; mt < 4; ++mt)
#pragma unroll
      for (int j = 0; j < 4; ++j) {
        const int row = m0 + wm + mt * 16 + l4 * 4 + j;
        const float v = acc[mt][nt][j] + bb;
        const int n = row >> 11, s = row & (S_LEN - 1);
        const size_t panel = (size_t)(n * NHEAD + hh);
        if (z == 0) {
          const size_t a = panel * (S_LEN * HDIM) + (size_t)(s >> 5) * 2048 +
                           (d >> 4) * 512 + ((d >> 3) & 1) * 256 + (s & 31) * 8 + (d & 7);
          Q[a] = (f16)(v * QSCALE);
        } else if (z == 1) {
          const size_t a = panel * (S_LEN * HDIM) + (size_t)(s >> 5) * 2048 +
                           (d >> 4) * 512 + ((d >> 3) & 1) * 256 + (s & 31) * 8 + (d & 7);
          Kh[a] = (f16)v;
        } else {
          const size_t a = panel * (S_LEN * HDIM) + (size_t)(s >> 6) * 4096 +
                           (d >> 5) * 2048 + ((s >> 4) & 3) * 512 + ((s >> 3) & 1) * 256 +
                           (d & 31) * 8 + (s & 7);
          Vt[a] = (f16)v;
        }
      }
  }
}

// ------- 64x128 f16 GEMM core (outproj) -------
__device__ __forceinline__ void gemm_core_sw64(const f16* __restrict__ A, const f16* __restrict__ B,
                                               char* lds, f32x4 acc[2][4]) {
  const int tid = threadIdx.x;
  const int wid = tid >> 6, lane = tid & 63;
  const int l15 = lane & 15, l4 = lane >> 4;
  const int wm = (wid >> 1) * 32, wn = (wid & 1) * 64;
  const int rr = tid >> 2, cc = tid & 3;
  const int ccs = cc ^ ((rr >> 1) & 3);                    // pre-swizzled source slot
  const f16* gA = A + (size_t)rr * DIM + ccs * 8;          // rows 0..63
  const f16* gB = B + (size_t)rr * DIM + ccs * 8;
  const int ldst = wid * 1024;

  gload16(gA,            lds + ldst);                      // A rows 0..63
  gload16(gB,            lds + 4096 + ldst);               // B rows 0..63
  gload16(gB + 64 * DIM, lds + 8192 + ldst);               // B rows 64..127
  __syncthreads();

  const int sw = (l15 >> 1) & 3;
  for (int kt = 0; kt < DIM / 32; ++kt) {
    char* cur = lds + (kt & 1) * 12288;
    if (kt + 1 < DIM / 32) {
      char* nxt = lds + ((kt + 1) & 1) * 12288;
      const f16* ga = gA + (kt + 1) * 32;
      const f16* gb = gB + (kt + 1) * 32;
      gload16(ga,            nxt + ldst);
      gload16(gb,            nxt + 4096 + ldst);
      gload16(gb + 64 * DIM, nxt + 8192 + ldst);
    }
    f16x8 af[2], bf[4];
#pragma unroll
    for (int mt = 0; mt < 2; ++mt)
      af[mt] = *(const f16x8*)(cur + (wm + mt * 16 + l15) * 64 + (l4 ^ sw) * 16);
#pragma unroll
    for (int nt = 0; nt < 4; ++nt)
      bf[nt] = *(const f16x8*)(cur + 4096 + (wn + nt * 16 + l15) * 64 + (l4 ^ sw) * 16);
#pragma unroll
    for (int mt = 0; mt < 2; ++mt)
#pragma unroll
      for (int nt = 0; nt < 4; ++nt)
        acc[mt][nt] = __builtin_amdgcn_mfma_f32_16x16x32_f16(af[mt], bf[nt], acc[mt][nt], 0, 0, 0);
    __syncthreads();
  }
}

// ---------------- output projection -> fp32 d_out (64-row tile, XCD-chunked) --------
// 16m x 4n chunks per XCD: A-panels stay exclusive (local), W fetched 4x less.
__global__ __launch_bounds__(256) void outproj_kernel(
    const f16* __restrict__ A, const f16* __restrict__ Wt,
    const float* __restrict__ bias, float* __restrict__ Out) {
  __shared__ __align__(16) char lds[24576];
  const int fid = (int)blockIdx.x;                 // 0..511 linear
  const int c = fid >> 6, i = fid & 63;            // chunk (XCD), index-in-chunk
  const int mt_ = (i & 15) + (c >> 1) * 16;        // 0..63
  const int nt_ = ((i >> 4) & 3) + (c & 1) * 4;    // 0..7
  const int m0 = mt_ * 64, n0 = nt_ * 128;
  f32x4 acc[2][4] = {};
  gemm_core_sw64(A + (size_t)m0 * DIM, Wt + (size_t)n0 * DIM, lds, acc);

  const int tid = threadIdx.x, wid = tid >> 6, lane = tid & 63;
  const int l15 = lane & 15, l4 = lane >> 4;
  const int wm = (wid >> 1) * 32, wn = (wid & 1) * 64;
#pragma unroll
  for (int nt = 0; nt < 4; ++nt) {
    const int col = n0 + wn + nt * 16 + l15;
    const float bb = bias[col];
#pragma unroll
    for (int mt = 0; mt < 2; ++mt)
#pragma unroll
      for (int j = 0; j < 4; ++j) {
        const int row = m0 + wm + mt * 16 + l4 * 4 + j;
        Out[(size_t)row * DIM + col] = acc[mt][nt][j] + bb;
      }
  }
}

// -------- flash attention (frozen best): reg-staged async-split (T14) + XCD swizzle (T1) ----
__global__ __launch_bounds__(256, 2) void attn_kernel(
    const f16* __restrict__ Q, const f16* __restrict__ K,
    const f16* __restrict__ Vt, f16* __restrict__ AO) {
  const int bid = blockIdx.x;
  const int sbid = (bid & 7) * 64 + (bid >> 3);    // bijective: 512 % 8 == 0
  const int qt = sbid & 15, h = (sbid >> 4) & 15, b = sbid >> 8;
  const int tid = threadIdx.x;
  const int lane = tid & 63, wid = tid >> 6;
  const int l31 = lane & 31, hi = lane >> 5;

  __shared__ __align__(16) char kv_lds[2][16384];  // [buf][K 8KB | V 8KB]

  const int q0 = qt * 128 + wid * 32;
  const size_t panel = (size_t)(b * NHEAD + h) * (S_LEN * HDIM);
  const f16* Qp = Q + panel + (size_t)(q0 >> 5) * 2048;
  const char* KpB = (const char*)(K + panel);
  const char* VpB = (const char*)(Vt + panel);

  f16x8 qf[4];
#pragma unroll
  for (int sk = 0; sk < 4; ++sk)
    qf[sk] = *(const f16x8*)(Qp + sk * 512 + hi * 256 + l31 * 8);

  f32x16 accO[2] = {};            // O^T[d][q]: dt in {0,1}, col=q=l31
  float lacc0 = 0.f, lacc1 = 0.f, lacc2 = 0.f, lacc3 = 0.f;

  auto LOADR = [&](int it, f32x4 (&R)[4]) {
    const char* gK = KpB + (size_t)it * 8192 + tid * 16;
    const char* gV = VpB + (size_t)it * 8192 + tid * 16;
    R[0] = *(const f32x4*)(gK);
    R[1] = *(const f32x4*)(gK + 4096);
    R[2] = *(const f32x4*)(gV);
    R[3] = *(const f32x4*)(gV + 4096);
  };
  auto WRITER = [&](const f32x4 (&R)[4], int buf) {
    char* p = &kv_lds[buf][(tid >> 6) * 1024 + (tid & 63) * 16];
    *(f32x4*)(p)         = R[0];
    *(f32x4*)(p + 4096)  = R[1];
    *(f32x4*)(p + 8192)  = R[2];
    *(f32x4*)(p + 12288) = R[3];
  };

  auto QK = [&](int buf, f32x16 (&st)[2]) {
    const char* lk = &kv_lds[buf][0];
    f16x8 kf[2][4];
#pragma unroll
    for (int tt = 0; tt < 2; ++tt)
#pragma unroll
      for (int sk = 0; sk < 4; ++sk)
        kf[tt][sk] = *(const f16x8*)(lk + tt * 4096 + sk * 1024 + lane * 16);
    __builtin_amdgcn_s_setprio(1);
#pragma unroll
    for (int tt = 0; tt < 2; ++tt) {
      st[tt] = (f32x16)(0.f);
#pragma unroll
      for (int sk = 0; sk < 4; ++sk)
        st[tt] = __builtin_amdgcn_mfma_f32_32x32x16_f16(kf[tt][sk], qf[sk], st[tt], 0, 0, 0);
    }
    __builtin_amdgcn_s_setprio(0);
  };

  auto PHASE = [&](f32x16 (&st)[2], int buf) {
    const char* lv = &kv_lds[buf][8192];
    f16x8 vf[2][4];
#pragma unroll
    for (int dt = 0; dt < 2; ++dt)
#pragma unroll
      for (int s = 0; s < 4; ++s)
        vf[dt][s] = *(const f16x8*)(lv + dt * 4096 + s * 1024 + lane * 16);

    u32 pk[2][8];
#pragma unroll
    for (int tt = 0; tt < 2; ++tt)
#pragma unroll
      for (int j = 0; j < 8; ++j) {
        const float p0 = fast_exp2(st[tt][2 * j]);
        const float p1 = fast_exp2(st[tt][2 * j + 1]);
        const float ps = p0 + p1;
        if (((tt * 8 + j) & 3) == 0) lacc0 += ps;
        else if (((tt * 8 + j) & 3) == 1) lacc1 += ps;
        else if (((tt * 8 + j) & 3) == 2) lacc2 += ps;
        else lacc3 += ps;
        union { hf16x2 h; u32 w; } cv;
        cv.h = __builtin_amdgcn_cvt_pkrtz(p0, p1);
        pk[tt][j] = cv.w;
      }

    __builtin_amdgcn_s_setprio(1);
#pragma unroll
    for (int s = 0; s < 4; ++s) {
      const int tt = s >> 1, sl = s & 1;
      u32 w0 = pk[tt][4 * sl + 0], w2 = pk[tt][4 * sl + 2];
      u32 w1 = pk[tt][4 * sl + 1], w3 = pk[tt][4 * sl + 3];
      asm("v_permlane32_swap_b32 %0, %1" : "+v"(w0), "+v"(w2));
      asm("v_permlane32_swap_b32 %0, %1" : "+v"(w1), "+v"(w3));
      union { u32 w[4]; f16x8 v; } pf;
      pf.w[0] = w0; pf.w[1] = w1; pf.w[2] = w2; pf.w[3] = w3;
      accO[0] = __builtin_amdgcn_mfma_f32_32x32x16_f16(vf[0][s], pf.v, accO[0], 0, 0, 0);
      accO[1] = __builtin_amdgcn_mfma_f32_32x32x16_f16(vf[1][s], pf.v, accO[1], 0, 0, 0);
    }
    __builtin_amdgcn_s_setprio(0);
  };

  const int NIT = S_LEN / 64;  // 32 (even)

  f32x4 RA[4], RB[4];
  f32x16 st[2];
  LOADR(0, RA);
  WRITER(RA, 0);               // compiler waits RA's vmcnt here (prologue only)
  LOADR(1, RB);                // in flight across the first barrier
  SYNCL();

  for (int it = 0; it < NIT; it += 2) {
    if (it + 2 < NIT) LOADR(it + 2, RA);
    QK(0, st);
    PHASE(st, 0);
    WRITER(RB, 1);             // vmcnt wait auto-inserted for RB only
    SYNCL();
    if (it + 3 < NIT) LOADR(it + 3, RB);
    QK(1, st);
    PHASE(st, 1);
    if (it + 2 < NIT) WRITER(RA, 0);
    SYNCL();
  }

  const float l_loc = (lacc0 + lacc1) + (lacc2 + lacc3);
  const float l_all = l_loc + __shfl_xor(l_loc, 32);
  const float inv = 1.f / l_all;
  f16* aop = AO + ((size_t)(b * S_LEN + q0 + l31)) * DIM + h * HDIM;
#pragma unroll
  for (int dt = 0; dt < 2; ++dt)
#pragma unroll
    for (int j = 0; j < 8; ++j) {
      union { f16x2 h; u32 w; } cv;
      cv.h[0] = (f16)(accO[dt][2 * j] * inv);
      cv.h[1] = (f16)(accO[dt][2 * j + 1] * inv);
      const int d = ((2 * j) & 3) + 8 * ((2 * j) >> 2) + 4 * hi + dt * 32;
      *(f16x2*)(aop + d) = cv.h;
    }
}

extern "C" void kernel_launch(void* const* d_in, const int* in_sizes, int n_in,
                              void* d_out, int out_size, void* d_ws, size_t ws_size,
                              hipStream_t stream) {
  (void)in_sizes; (void)n_in; (void)out_size; (void)ws_size;
  const float* q  = (const float*)d_in[0];
  const float* k  = (const float*)d_in[1];
  const float* v  = (const float*)d_in[2];
  const float* Wq = (const float*)d_in[3];
  const float* bq = (const float*)d_in[4];
  const float* Wk = (const float*)d_in[5];
  const float* bk = (const float*)d_in[6];
  const float* Wv = (const float*)d_in[7];
  const float* bv = (const float*)d_in[8];
  const float* Wp = (const float*)d_in[9];
  const float* bp = (const float*)d_in[10];

  char* ws = (char*)d_ws;
  f16* Xq  = (f16*)(ws + OFF_XQ);
  f16* Xk  = (f16*)(ws + OFF_XK);
  f16* Xv  = (f16*)(ws + OFF_XV);
  f16* Wt  = (f16*)(ws + OFF_WT);
  f16* Qs  = (f16*)(ws + OFF_Q);
  f16* Kh  = (f16*)(ws + OFF_K);
  f16* Vts = (f16*)(ws + OFF_VT);
  f16* AO  = (f16*)(ws + OFF_AO);

  prep_kernel<<<dim3(2048, 4, 1), 256, 0, stream>>>(q, k, v, Wq, Wk, Wv, Wp, Xq, Xk, Xv, Wt);
  proj_kernel<<<dim3(32, 8, 3), 256, 0, stream>>>(Xq, Xk, Xv, Wt, bq, bk, bv, Qs, Kh, Vts);
  attn_kernel<<<dim3(512, 1, 1), 256, 0, stream>>>(Qs, Kh, Vts, AO);
  outproj_kernel<<<dim3(512, 1, 1), 256, 0, stream>>>(AO, Wt + 3ull * DIM * DIM, bp, (float*)d_out);
}